// Round 4
// baseline (106.255 us; speedup 1.0000x reference)
//
#include <hip/hip_runtime.h>
#include <hip/hip_bf16.h>

#define IN_CNT 64
#define FEAT   1024
#define BATCH  256

#define BM 256
#define BN 256
#define BK 64
#define KT (FEAT / BK)   // 16 K-tiles

typedef __attribute__((ext_vector_type(4))) float f32x4;
typedef __attribute__((ext_vector_type(4))) short bf16x4;   // 4 bf16 = 8 B
typedef __attribute__((ext_vector_type(8))) short bf16x8;   // 8 bf16 = one MFMA A/B frag

__device__ __forceinline__ short f2bf(float f) {
    __hip_bfloat16 h = __float2bfloat16(f);
    return __builtin_bit_cast(short, h);
}

__device__ __forceinline__ bf16x4 pack4(f32x4 a) {
    bf16x4 v;
    v[0] = f2bf(a[0]); v[1] = f2bf(a[1]); v[2] = f2bf(a[2]); v[3] = f2bf(a[3]);
    return v;
}

// Barrier that drains LDS ops (cross-wave visibility) but NOT vmcnt ->
// prefetch global loads stay in flight across the barrier (T4).
__device__ __forceinline__ void barrier_nodrain() {
    asm volatile("s_waitcnt lgkmcnt(0)" ::: "memory");
    __builtin_amdgcn_s_barrier();
    asm volatile("" ::: "memory");
}

__global__ __launch_bounds__(512, 2)
void split_linear_kernel(const float* __restrict__ x,
                         const float* __restrict__ W,
                         float* __restrict__ out)
{
    // 2 bufs x (A 256x64 bf16 = 32KB + B 32KB) = 128 KB.
    // buf b at short offset b*32768; A +0, B +16384. Row = 64 shorts = 128 B.
    __shared__ __align__(16) short lds[65536];

    const int tid = threadIdx.x;

    // bijective XCD swizzle (256 % 8 == 0): the 4 same-gi blocks share one XCD L2.
    const int bid = blockIdx.x;
    const int swz = ((bid & 7) << 5) | (bid >> 3);
    const int gi   = swz >> 2;            // 0..63
    const int ncol = (swz & 3) << 8;      // 0/256/512/768

    const int lane = tid & 63;
    const int wid  = tid >> 6;
    const int wm   = wid >> 2;            // 0..1
    const int wn   = wid & 3;             // 0..3
    const int lr   = lane & 15;
    const int lh   = lane >> 4;

    // ---- staging coords: wave-instr = 4 rows x 16 lanes x 16 B = 1 KB, 8 full lines
    const int srow = wid * 4 + lh;        // 0..31 (+ i*32)
    const int gpos = lr;                  // 16-B granule within the 256-B K slab
    const float* Abase = x + ((size_t)srow * IN_CNT + gi) * FEAT + gpos * 4;
    const float* Bbase = W + ((size_t)gi * FEAT + ncol + srow) * FEAT + gpos * 4;

    f32x4 ra[8], rb[8];
    f32x4 acc[8][4];
#pragma unroll
    for (int m = 0; m < 8; ++m)
#pragma unroll
        for (int n = 0; n < 4; ++n)
            acc[m][n] = (f32x4){0.f, 0.f, 0.f, 0.f};

    auto LOADT = [&](int kt) {
#pragma unroll
        for (int i = 0; i < 8; ++i) {
            ra[i] = *(const f32x4*)(Abase + (size_t)kt * BK + (size_t)i * (32 * IN_CNT * FEAT));
            rb[i] = *(const f32x4*)(Bbase + (size_t)kt * BK + (size_t)i * (32 * FEAT));
        }
    };

    // even-XOR swizzle: granule g of row r lands at s8 = g ^ (2*(r&7)).
    // Keeps frag pairs {2t,2t+1} adjacent -> b128 read at slot16 t^(r&7), 2-way max.
    auto WRITET = [&](int b) {
        short* base = lds + b * 32768;
#pragma unroll
        for (int i = 0; i < 8; ++i) {
            const int r  = srow + i * 32;
            const int s8 = gpos ^ ((r & 7) << 1);
            *(bf16x4*)&base[r * 64 + s8 * 4]         = pack4(ra[i]);
            *(bf16x4*)&base[16384 + r * 64 + s8 * 4] = pack4(rb[i]);
        }
    };

    auto COMPUTE = [&](int b) {
        const short* baseA = lds + b * 32768;
        const short* baseB = baseA + 16384;
#pragma unroll
        for (int ks = 0; ks < 2; ++ks) {
            const int t = ks * 4 + lh;    // frag slot16 before swizzle
            bf16x8 bf[4];
#pragma unroll
            for (int nf = 0; nf < 4; ++nf) {
                const int r = wn * 64 + nf * 16 + lr;
                bf[nf] = *(const bf16x8*)&baseB[r * 64 + ((t ^ (r & 7)) << 3)];
            }
#pragma unroll
            for (int mf = 0; mf < 8; ++mf) {
                const int r = wm * 128 + mf * 16 + lr;
                bf16x8 af = *(const bf16x8*)&baseA[r * 64 + ((t ^ (r & 7)) << 3)];
#pragma unroll
                for (int nf = 0; nf < 4; ++nf)
                    acc[mf][nf] = __builtin_amdgcn_mfma_f32_16x16x32_bf16(
                        af, bf[nf], acc[mf][nf], 0, 0, 0);
            }
        }
    };

    // ---- prologue
    LOADT(0);
    WRITET(0);
    LOADT(1);
    barrier_nodrain();

    // ---- main loop: stage tile kt+1 (regs->LDS), refill regs with kt+2, compute kt
    for (int kt = 0; kt < KT; ++kt) {
        const int b = kt & 1;
        if (kt + 1 < KT) WRITET(b ^ 1);
        if (kt + 2 < KT) LOADT(kt + 2);
        COMPUTE(b);
        barrier_nodrain();
    }

    // ---- epilogue: stripe-transpose through LDS -> contiguous f32x4 stores.
    // C/D frag layout: col = lane&15 (n), row = lh*4 + j (m)  [m89-verified]
    // Padded row stride 260 floats kills the 4-way write conflict.
#define ELD 260
    float* elds = (float*)lds;   // 64 rows x 260 floats = 66.6 KB scratch
#pragma unroll
    for (int s = 0; s < 4; ++s) {               // 4 stripes of 64 m-rows
        barrier_nodrain();                       // previous stripe fully read
        if (wm == (s >> 1)) {
            const int mfb = (s & 1) * 4;
#pragma unroll
            for (int f = 0; f < 4; ++f)
#pragma unroll
                for (int nf = 0; nf < 4; ++nf)
#pragma unroll
                    for (int j = 0; j < 4; ++j)
                        elds[(f * 16 + lh * 4 + j) * ELD + wn * 64 + nf * 16 + lr]
                            = acc[mfb + f][nf][j];
        }
        barrier_nodrain();
#pragma unroll
        for (int rr = 0; rr < 8; ++rr) {         // wave w stores rows w*8..w*8+7
            const int rowl = wid * 8 + rr;
            f32x4 v = *(const f32x4*)&elds[rowl * ELD + lane * 4];
            const int m = s * 64 + rowl;
            *(f32x4*)&out[((size_t)m * IN_CNT + gi) * FEAT + ncol + lane * 4] = v;
        }
    }
#undef ELD
}

extern "C" void kernel_launch(void* const* d_in, const int* in_sizes, int n_in,
                              void* d_out, int out_size, void* d_ws, size_t ws_size,
                              hipStream_t stream) {
    const float* x   = (const float*)d_in[0];
    const float* W   = (const float*)d_in[1];
    float*       out = (float*)d_out;

    dim3 grid(IN_CNT * (FEAT / BN));   // 256 blocks: one 256x256 tile each
    dim3 block(512);
    hipLaunchKernelGGL(split_linear_kernel, grid, block, 0, stream, x, W, out);
}

// Round 5
// 105.237 us; speedup vs baseline: 1.0097x; 1.0097x over previous
//
#include <hip/hip_runtime.h>
#include <hip/hip_bf16.h>

#define IN_CNT 64
#define FEAT   1024
#define BATCH  256

#define BM 256
#define BN 256
#define BK 32
#define KT (FEAT / BK)   // 32 K-tiles

typedef __attribute__((ext_vector_type(4))) float f32x4;
typedef __attribute__((ext_vector_type(4))) short bf16x4;   // 4 bf16 = 8 B
typedef __attribute__((ext_vector_type(8))) short bf16x8;   // 8 bf16 = one MFMA A/B frag

__device__ __forceinline__ short f2bf(float f) {
    __hip_bfloat16 h = __float2bfloat16(f);
    return __builtin_bit_cast(short, h);
}

__device__ __forceinline__ bf16x4 pack4(f32x4 a) {
    bf16x4 v;
    v[0] = f2bf(a[0]); v[1] = f2bf(a[1]); v[2] = f2bf(a[2]); v[3] = f2bf(a[3]);
    return v;
}

// Barrier that drains LDS ops (cross-wave visibility) but NOT vmcnt ->
// prefetch global loads stay in flight across the barrier (T4).
__device__ __forceinline__ void barrier_nodrain() {
    asm volatile("s_waitcnt lgkmcnt(0)" ::: "memory");
    __builtin_amdgcn_s_barrier();
    asm volatile("" ::: "memory");
}

__global__ __launch_bounds__(512, 2)
void split_linear_kernel(const float* __restrict__ x,
                         const float* __restrict__ W,
                         float* __restrict__ out)
{
    // Main loop: 2 bufs x (A 256x32 bf16 = 16KB + B 16KB) = 64 KB.
    // LDS tile layout: 128-B superrows (2 rows of 32 bf16), 8 slots of 16 B,
    // slot XOR (sr&7)  -- R4's measured-zero-conflict geometry.
    // Epilogue reuses LDS as float[64][260] (66.6 KB).
    __shared__ __align__(16) short lds[33280];

    const int tid = threadIdx.x;

    // bijective XCD swizzle (256 % 8 == 0): the 4 same-gi blocks share one XCD L2.
    const int bid = blockIdx.x;
    const int swz = ((bid & 7) << 5) | (bid >> 3);
    const int gi   = swz >> 2;            // 0..63
    const int ncol = (swz & 3) << 8;      // 0/256/512/768

    const int lane = tid & 63;
    const int wid  = tid >> 6;
    const int wm   = wid >> 2;            // 0..1
    const int wn   = wid & 3;             // 0..3
    const int lr   = lane & 15;
    const int lh   = lane >> 4;

    // ---- staging coords: wave-instr = 8 rows x 8 lanes x 16 B = 8 full lines
    const int srow = tid >> 3;            // 0..63 (+ p*64)
    const int g    = tid & 7;             // 16-B granule within the 128-B K slab
    // swizzled write short-offset within superrow (constant across passes,
    // since p*64 rows = p*32 superrows == 0 mod 8):
    const int wsh = (((((srow & 1) << 2) + (g >> 1)) ^ ((srow >> 1) & 7)) << 3)
                    + ((g & 1) << 2);

    const float* Abase = x + ((size_t)srow * IN_CNT + gi) * FEAT + g * 4;
    const float* Bbase = W + ((size_t)gi * FEAT + ncol + srow) * FEAT + g * 4;

    f32x4 sA[2][4], sB[2][4];             // two staging sets (set = tile & 1)
    f32x4 acc[8][4];
#pragma unroll
    for (int m = 0; m < 8; ++m)
#pragma unroll
        for (int n = 0; n < 4; ++n)
            acc[m][n] = (f32x4){0.f, 0.f, 0.f, 0.f};

    auto LOADT = [&](int kt, int s) {
#pragma unroll
        for (int p = 0; p < 4; ++p) {
            sA[s][p] = *(const f32x4*)(Abase + (size_t)kt * BK + (size_t)p * (64 * IN_CNT * FEAT));
            sB[s][p] = *(const f32x4*)(Bbase + (size_t)kt * BK + (size_t)p * (64 * FEAT));
        }
    };

    auto WRITET = [&](int s, int b) {
        short* base = lds + b * 16384;
#pragma unroll
        for (int p = 0; p < 4; ++p) {
            const int sr = (srow >> 1) + p * 32;   // superrow
            *(bf16x4*)&base[sr * 64 + wsh]        = pack4(sA[s][p]);
            *(bf16x4*)&base[8192 + sr * 64 + wsh] = pack4(sB[s][p]);
        }
    };

    // frag read slot (constant across mf/nf: mf*8, nf*8 superrows == 0 mod 8)
    const int rsh = ((((lr & 1) << 2) + lh) ^ ((lr >> 1) & 7)) << 3;

    auto COMPUTE = [&](int b) {
        const short* baseA = lds + b * 16384;
        const short* baseB = baseA + 8192;
        bf16x8 bf[4];
#pragma unroll
        for (int nf = 0; nf < 4; ++nf) {
            const int sr = wn * 32 + nf * 8 + (lr >> 1);
            bf[nf] = *(const bf16x8*)&baseB[sr * 64 + rsh];
        }
#pragma unroll
        for (int mf = 0; mf < 8; ++mf) {
            const int sr = wm * 64 + mf * 8 + (lr >> 1);
            bf16x8 af = *(const bf16x8*)&baseA[sr * 64 + rsh];
#pragma unroll
            for (int nf = 0; nf < 4; ++nf)
                acc[mf][nf] = __builtin_amdgcn_mfma_f32_16x16x32_bf16(
                    af, bf[nf], acc[mf][nf], 0, 0, 0);
        }
    };

    // ---- prologue: tiles 0,1 in regs; tile 0 staged; set0 refilled with tile 2
    LOADT(0, 0);
    LOADT(1, 1);
    WRITET(0, 0);
    LOADT(2, 0);
    barrier_nodrain();

    // ---- main loop, 2 tiles per trip; load->write distance = 2 phases
    for (int kt = 0; kt < KT; kt += 2) {
        // even phase: stage tile kt+1 (set1->buf1); refill set1 with kt+3; compute kt
        WRITET(1, 1);
        if (kt + 3 < KT) LOADT(kt + 3, 1);
        COMPUTE(0);
        barrier_nodrain();
        // odd phase: stage tile kt+2 (set0->buf0); refill set0 with kt+4; compute kt+1
        if (kt + 2 < KT) WRITET(0, 0);
        if (kt + 4 < KT) LOADT(kt + 4, 0);
        COMPUTE(1);
        barrier_nodrain();
    }

    // ---- epilogue: stripe-transpose through LDS -> contiguous f32x4 stores.
    // C/D frag layout: col = lane&15 (n), row = lh*4 + j (m)  [m89-verified]
    // Padded row stride 260 floats kills the 4-way write conflict.
#define ELD 260
    float* elds = (float*)lds;   // 64 rows x 260 floats = 66.6 KB scratch
#pragma unroll
    for (int s = 0; s < 4; ++s) {               // 4 stripes of 64 m-rows
        barrier_nodrain();                       // previous stripe fully read
        if (wm == (s >> 1)) {
            const int mfb = (s & 1) * 4;
#pragma unroll
            for (int f = 0; f < 4; ++f)
#pragma unroll
                for (int nf = 0; nf < 4; ++nf)
#pragma unroll
                    for (int j = 0; j < 4; ++j)
                        elds[(f * 16 + lh * 4 + j) * ELD + wn * 64 + nf * 16 + lr]
                            = acc[mfb + f][nf][j];
        }
        barrier_nodrain();
#pragma unroll
        for (int rr = 0; rr < 8; ++rr) {         // wave w stores rows w*8..w*8+7
            const int rowl = wid * 8 + rr;
            f32x4 v = *(const f32x4*)&elds[rowl * ELD + lane * 4];
            const int m = s * 64 + rowl;
            *(f32x4*)&out[((size_t)m * IN_CNT + gi) * FEAT + ncol + lane * 4] = v;
        }
    }
#undef ELD
}

extern "C" void kernel_launch(void* const* d_in, const int* in_sizes, int n_in,
                              void* d_out, int out_size, void* d_ws, size_t ws_size,
                              hipStream_t stream) {
    const float* x   = (const float*)d_in[0];
    const float* W   = (const float*)d_in[1];
    float*       out = (float*)d_out;

    dim3 grid(IN_CNT * (FEAT / BN));   // 256 blocks: one 256x256 tile each
    dim3 block(512);
    hipLaunchKernelGGL(split_linear_kernel, grid, block, 0, stream, x, W, out);
}

// Round 6
// 94.720 us; speedup vs baseline: 1.1218x; 1.1110x over previous
//
#include <hip/hip_runtime.h>
#include <hip/hip_bf16.h>

#define IN_CNT 64
#define FEAT   1024
#define BATCH  256

#define BM 256
#define BN 256
#define BK 32
#define KT (FEAT / BK)   // 32 K-tiles

typedef __attribute__((ext_vector_type(4))) float f32x4;
typedef __attribute__((ext_vector_type(8))) short bf16x8;   // 8 bf16 = one MFMA A/B frag

__device__ __forceinline__ short f2bf(float f) {
    __hip_bfloat16 h = __float2bfloat16(f);
    return __builtin_bit_cast(short, h);
}

__device__ __forceinline__ bf16x8 pack8(f32x4 a, f32x4 b) {
    bf16x8 v;
    v[0] = f2bf(a[0]); v[1] = f2bf(a[1]); v[2] = f2bf(a[2]); v[3] = f2bf(a[3]);
    v[4] = f2bf(b[0]); v[5] = f2bf(b[1]); v[6] = f2bf(b[2]); v[7] = f2bf(b[3]);
    return v;
}

// raw barrier + LDS drain only; vmcnt is managed manually (counted, never 0 mid-loop)
__device__ __forceinline__ void barrier_lgkm() {
    asm volatile("s_waitcnt lgkmcnt(0)" ::: "memory");
    __builtin_amdgcn_s_barrier();
    asm volatile("" ::: "memory");
}

// async global->LDS DMA, 16B per lane. LDS dest = wave-uniform base + lane*16.
__device__ __forceinline__ void gload16(const float* g, float* l) {
    __builtin_amdgcn_global_load_lds(
        (const __attribute__((address_space(1))) void*)g,
        (__attribute__((address_space(3))) void*)l, 16, 0, 0);
}

__global__ __launch_bounds__(512, 2)
void split_linear_kernel(const float* __restrict__ x,
                         const float* __restrict__ W,
                         float* __restrict__ out)
{
    // fp32 tiles in LDS: 2 bufs x (A 256x32 = 32KB + B 32KB) = 128 KB.
    // buf b at float offset b*16384; A +0, B +8192. Row = 32 floats = 128 B,
    // 8 granules of 16 B. Swizzle: LDS slot s of row r holds global granule
    // s ^ (r&7) (applied on the DMA *source* address; DMA writes linearly).
    __shared__ __align__(16) float lds[32768];

    const int tid = threadIdx.x;

    // bijective XCD swizzle (256 % 8 == 0): the 4 same-gi blocks share one XCD L2.
    const int bid = blockIdx.x;
    const int swz = ((bid & 7) << 5) | (bid >> 3);
    const int gi   = swz >> 2;            // 0..63
    const int ncol = (swz & 3) << 8;      // 0/256/512/768

    const int lane = tid & 63;
    const int wid  = tid >> 6;
    const int wm   = wid >> 2;            // 0..1
    const int wn   = wid & 3;             // 0..3
    const int lr   = lane & 15;
    const int lh   = lane >> 4;

    // ---- DMA source coords: chunk = 8 rows x 8 granules; lane L -> row L>>3,
    // fetches granule (L&7)^(L>>3) so LDS slot (L&7) holds the swizzled granule.
    const int lrow = lane >> 3;                 // 0..7
    const int lgr  = (lane & 7) ^ lrow;         // pre-swizzled source granule
    const float* Asrc = x + ((size_t)lrow * IN_CNT + gi) * FEAT + lgr * 4;
    const float* Bsrc = W + ((size_t)gi * FEAT + ncol + lrow) * FEAT + lgr * 4;

    f32x4 acc[8][4];
#pragma unroll
    for (int m = 0; m < 8; ++m)
#pragma unroll
        for (int n = 0; n < 4; ++n)
            acc[m][n] = (f32x4){0.f, 0.f, 0.f, 0.f};

    // issue one tile's DMA: 64 chunk-instrs over 8 waves -> 4 A + 4 B per wave
    auto ISSUE = [&](int kt, int b) {
        float* base = lds + b * 16384;
        const float* a0 = Asrc + (size_t)kt * BK;
        const float* b0 = Bsrc + (size_t)kt * BK;
#pragma unroll
        for (int i = 0; i < 4; ++i) {
            const int c = wid * 4 + i;          // chunk 0..31 (8 rows each)
            gload16(a0 + (size_t)c * (8 * IN_CNT * FEAT), base + c * 256);
            gload16(b0 + (size_t)c * (8 * FEAT),          base + 8192 + c * 256);
        }
    };

    // read fp32 frag (k = lh*8 .. lh*8+7) from swizzled LDS row, cvt to bf16
    const int sl0 = ((2 * lh)     ^ (lr & 7)) << 2;   // float offsets of the 2 slots
    const int sl1 = ((2 * lh + 1) ^ (lr & 7)) << 2;

    auto COMPUTE = [&](int b) {
        const float* bufA = lds + b * 16384;
        const float* bufB = bufA + 8192;
        bf16x8 bfr[4];
#pragma unroll
        for (int nf = 0; nf < 4; ++nf) {
            const float* rp = bufB + (wn * 64 + nf * 16 + lr) * 32;
            bfr[nf] = pack8(*(const f32x4*)(rp + sl0), *(const f32x4*)(rp + sl1));
        }
#pragma unroll
        for (int mf = 0; mf < 8; ++mf) {
            const float* rp = bufA + (wm * 128 + mf * 16 + lr) * 32;
            bf16x8 af = pack8(*(const f32x4*)(rp + sl0), *(const f32x4*)(rp + sl1));
#pragma unroll
            for (int nf = 0; nf < 4; ++nf)
                acc[mf][nf] = __builtin_amdgcn_mfma_f32_16x16x32_bf16(
                    af, bfr[nf], acc[mf][nf], 0, 0, 0);
        }
    };

    // ---- prologue: tiles 0,1 in flight; wait tile 0 (8 newest stay in flight)
    ISSUE(0, 0);
    ISSUE(1, 1);
    asm volatile("s_waitcnt vmcnt(8)" ::: "memory");
    __builtin_amdgcn_s_barrier();
    asm volatile("" ::: "memory");

    // ---- main loop: compute k | barrier | issue k+2 into k's buf, wait k+1 | barrier
    for (int k = 0; k < KT; ++k) {
        const int b = k & 1;
        COMPUTE(b);
        barrier_lgkm();                        // all waves done reading buf b
        if (k + 2 < KT) {
            ISSUE(k + 2, b);
            asm volatile("s_waitcnt vmcnt(8)" ::: "memory");   // tile k+1 landed
        } else {
            asm volatile("s_waitcnt vmcnt(0)" ::: "memory");   // tail drain
        }
        __builtin_amdgcn_s_barrier();
        asm volatile("" ::: "memory");
    }

    // ---- epilogue: stripe-transpose through LDS -> contiguous f32x4 stores.
    // C/D frag layout: col = lane&15 (n), row = lh*4 + j (m)  [m89-verified]
    // Padded row stride 260 floats: conflict-free writes.
#define ELD 260
    float* elds = lds;   // 64 rows x 260 floats = 66.6 KB scratch (have 128 KB)
#pragma unroll
    for (int s = 0; s < 4; ++s) {               // 4 stripes of 64 m-rows
        barrier_lgkm();                          // previous stripe fully read
        if (wm == (s >> 1)) {
            const int mfb = (s & 1) * 4;
#pragma unroll
            for (int f = 0; f < 4; ++f)
#pragma unroll
                for (int nf = 0; nf < 4; ++nf)
#pragma unroll
                    for (int j = 0; j < 4; ++j)
                        elds[(f * 16 + lh * 4 + j) * ELD + wn * 64 + nf * 16 + lr]
                            = acc[mfb + f][nf][j];
        }
        barrier_lgkm();
#pragma unroll
        for (int rr = 0; rr < 8; ++rr) {         // wave w stores rows w*8..w*8+7
            const int rowl = wid * 8 + rr;
            f32x4 v = *(const f32x4*)&elds[rowl * ELD + lane * 4];
            const int m = s * 64 + rowl;
            *(f32x4*)&out[((size_t)m * IN_CNT + gi) * FEAT + ncol + lane * 4] = v;
        }
    }
#undef ELD
}

extern "C" void kernel_launch(void* const* d_in, const int* in_sizes, int n_in,
                              void* d_out, int out_size, void* d_ws, size_t ws_size,
                              hipStream_t stream) {
    const float* x   = (const float*)d_in[0];
    const float* W   = (const float*)d_in[1];
    float*       out = (float*)d_out;

    dim3 grid(IN_CNT * (FEAT / BN));   // 256 blocks: one 256x256 tile each
    dim3 block(512);
    hipLaunchKernelGGL(split_linear_kernel, grid, block, 0, stream, x, W, out);
}

// Round 7
// 94.187 us; speedup vs baseline: 1.1281x; 1.0057x over previous
//
#include <hip/hip_runtime.h>
#include <hip/hip_bf16.h>

#define IN_CNT 64
#define FEAT   1024
#define BATCH  256

#define BM 256
#define BN 256
#define BK 32
#define KT (FEAT / BK)   // 32 K-tiles

typedef __attribute__((ext_vector_type(4))) float f32x4;
typedef __attribute__((ext_vector_type(8))) short bf16x8;   // 8 bf16 = one MFMA A/B frag

__device__ __forceinline__ short f2bf(float f) {
    __hip_bfloat16 h = __float2bfloat16(f);
    return __builtin_bit_cast(short, h);
}

__device__ __forceinline__ bf16x8 pack8(f32x4 a, f32x4 b) {
    bf16x8 v;
    v[0] = f2bf(a[0]); v[1] = f2bf(a[1]); v[2] = f2bf(a[2]); v[3] = f2bf(a[3]);
    v[4] = f2bf(b[0]); v[5] = f2bf(b[1]); v[6] = f2bf(b[2]); v[7] = f2bf(b[3]);
    return v;
}

// barrier + LDS drain only; vmcnt managed manually (counted, never 0 mid-loop)
__device__ __forceinline__ void barrier_lgkm() {
    asm volatile("s_waitcnt lgkmcnt(0)" ::: "memory");
    __builtin_amdgcn_s_barrier();
    asm volatile("" ::: "memory");
}

// async global->LDS DMA, 16B per lane. LDS dest = wave-uniform base + lane*16.
__device__ __forceinline__ void gload16(const float* g, float* l) {
    __builtin_amdgcn_global_load_lds(
        (const __attribute__((address_space(1))) void*)g,
        (__attribute__((address_space(3))) void*)l, 16, 0, 0);
}

__global__ __launch_bounds__(512, 2)
void split_linear_kernel(const float* __restrict__ x,
                         const float* __restrict__ W,
                         float* __restrict__ out)
{
    // fp32 tiles in LDS: 2 bufs x (A 256x32 = 32KB + B 32KB) = 128 KB.
    // buf b at float offset b*16384; A +0, B +8192. Row = 32 floats = 128 B,
    // 8 granules of 16 B. Swizzle: LDS slot s of row r holds global granule
    // s ^ (r&7) (applied on the DMA *source* address; DMA writes linearly).
    __shared__ __align__(16) float lds[32768];

    const int tid = threadIdx.x;

    // bijective XCD swizzle (256 % 8 == 0): the 4 same-gi blocks share one XCD L2.
    const int bid = blockIdx.x;
    const int swz = ((bid & 7) << 5) | (bid >> 3);
    const int gi   = swz >> 2;            // 0..63
    const int ncol = (swz & 3) << 8;      // 0/256/512/768

    const int lane = tid & 63;
    const int wid  = tid >> 6;
    const int wm   = wid >> 2;            // 0..1
    const int wn   = wid & 3;             // 0..3
    const int lr   = lane & 15;
    const int lh   = lane >> 4;

    // ---- DMA source coords: chunk = 8 rows x 8 granules; lane L -> row L>>3,
    // fetches granule (L&7)^(L>>3) so LDS slot (L&7) holds the swizzled granule.
    const int lrow = lane >> 3;                 // 0..7
    const int lgr  = (lane & 7) ^ lrow;         // pre-swizzled source granule
    const float* Asrc = x + ((size_t)lrow * IN_CNT + gi) * FEAT + lgr * 4;
    const float* Bsrc = W + ((size_t)gi * FEAT + ncol + lrow) * FEAT + lgr * 4;

    f32x4 acc[8][4];
#pragma unroll
    for (int m = 0; m < 8; ++m)
#pragma unroll
        for (int n = 0; n < 4; ++n)
            acc[m][n] = (f32x4){0.f, 0.f, 0.f, 0.f};

    // stage full A (or B) tile kt into buf bb: 32 chunks, wave w takes 4
    auto STAGE_A = [&](int kt, int bb) {
        float* base = lds + bb * 16384;
        const float* a0 = Asrc + (size_t)kt * BK;
#pragma unroll
        for (int i = 0; i < 4; ++i) {
            const int c = wid * 4 + i;          // rows 8c..8c+7
            gload16(a0 + (size_t)c * (8 * IN_CNT * FEAT), base + c * 256);
        }
    };
    auto STAGE_B = [&](int kt, int bb) {
        float* base = lds + bb * 16384 + 8192;
        const float* b0 = Bsrc + (size_t)kt * BK;
#pragma unroll
        for (int i = 0; i < 4; ++i) {
            const int c = wid * 4 + i;
            gload16(b0 + (size_t)c * (8 * FEAT), base + c * 256);
        }
    };

    // read fp32 frag (k = lh*8 .. lh*8+7) from swizzled LDS row, cvt to bf16
    const int sl0 = ((2 * lh)     ^ (lr & 7)) << 2;   // float offsets of the 2 slots
    const int sl1 = ((2 * lh + 1) ^ (lr & 7)) << 2;

    bf16x8 bfr[4];                        // B frags persist across both phases
    auto READ_B = [&](int bb) {
        const float* bufB = lds + bb * 16384 + 8192;
#pragma unroll
        for (int nf = 0; nf < 4; ++nf) {
            const float* rp = bufB + (wn * 64 + nf * 16 + lr) * 32;
            bfr[nf] = pack8(*(const f32x4*)(rp + sl0), *(const f32x4*)(rp + sl1));
        }
    };
    auto MFMA_HALF = [&](int bb, int ph) {          // mf in [ph*4, ph*4+4)
        const float* bufA = lds + bb * 16384;
#pragma unroll
        for (int m4 = 0; m4 < 4; ++m4) {
            const int mf = ph * 4 + m4;
            const float* rp = bufA + (wm * 128 + mf * 16 + lr) * 32;
            bf16x8 af = pack8(*(const f32x4*)(rp + sl0), *(const f32x4*)(rp + sl1));
#pragma unroll
            for (int nf = 0; nf < 4; ++nf)
                acc[mf][nf] = __builtin_amdgcn_mfma_f32_16x16x32_bf16(
                    af, bfr[nf], acc[mf][nf], 0, 0, 0);
        }
    };

    // ---- prologue: B(0), A(0), B(1) in flight; wait B(0),A(0); B(1) stays out
    STAGE_B(0, 0);
    STAGE_A(0, 0);
    STAGE_B(1, 1);
    asm volatile("s_waitcnt vmcnt(4)" ::: "memory");
    __builtin_amdgcn_s_barrier();
    asm volatile("" ::: "memory");

    // ---- main loop: 2 phases per tile, stage spread into phases (T3),
    //      counted vmcnt once per tile (T4), setprio around MFMA (T5)
    for (int t = 0; t < KT; ++t) {
        const int bb = t & 1;
        // P0: read B(all)+A(mf0-3) of buf bb; issue A(t+1) -> buf bb^1
        READ_B(bb);
        if (t + 1 < KT) STAGE_A(t + 1, bb ^ 1);
        __builtin_amdgcn_s_setprio(1);
        MFMA_HALF(bb, 0);
        __builtin_amdgcn_s_setprio(0);
        barrier_lgkm();
        // P1: read A(mf4-7); issue B(t+2) -> buf bb (B region freed at P0 barrier)
        if (t + 2 < KT) STAGE_B(t + 2, bb);
        __builtin_amdgcn_s_setprio(1);
        MFMA_HALF(bb, 1);
        __builtin_amdgcn_s_setprio(0);
        // gate: tile t+1 fully landed before next phase reads buf bb^1;
        // tile t+2's B (4 newest gloads) stays in flight
        if (t + 2 < KT) {
            asm volatile("s_waitcnt vmcnt(4)" ::: "memory");
        } else {
            asm volatile("s_waitcnt vmcnt(0)" ::: "memory");
        }
        __builtin_amdgcn_s_barrier();
        asm volatile("" ::: "memory");
    }

    // ---- epilogue: stripe-transpose through LDS -> contiguous f32x4 stores.
    // C/D frag layout: col = lane&15 (n), row = lh*4 + j (m)  [m89-verified]
#define ELD 260
    float* elds = lds;   // 64 rows x 260 floats = 66.6 KB scratch (have 128 KB)
#pragma unroll
    for (int s = 0; s < 4; ++s) {               // 4 stripes of 64 m-rows
        barrier_lgkm();                          // previous stripe fully read
        if (wm == (s >> 1)) {
            const int mfb = (s & 1) * 4;
#pragma unroll
            for (int f = 0; f < 4; ++f)
#pragma unroll
                for (int nf = 0; nf < 4; ++nf)
#pragma unroll
                    for (int j = 0; j < 4; ++j)
                        elds[(f * 16 + lh * 4 + j) * ELD + wn * 64 + nf * 16 + lr]
                            = acc[mfb + f][nf][j];
        }
        barrier_lgkm();
#pragma unroll
        for (int rr = 0; rr < 8; ++rr) {         // wave w stores rows w*8..w*8+7
            const int rowl = wid * 8 + rr;
            f32x4 v = *(const f32x4*)&elds[rowl * ELD + lane * 4];
            const int m = s * 64 + rowl;
            *(f32x4*)&out[((size_t)m * IN_CNT + gi) * FEAT + ncol + lane * 4] = v;
        }
    }
#undef ELD
}

extern "C" void kernel_launch(void* const* d_in, const int* in_sizes, int n_in,
                              void* d_out, int out_size, void* d_ws, size_t ws_size,
                              hipStream_t stream) {
    const float* x   = (const float*)d_in[0];
    const float* W   = (const float*)d_in[1];
    float*       out = (float*)d_out;

    dim3 grid(IN_CNT * (FEAT / BN));   // 256 blocks: one 256x256 tile each
    dim3 block(512);
    hipLaunchKernelGGL(split_linear_kernel, grid, block, 0, stream, x, W, out);
}